// Round 6
// baseline (811.409 us; speedup 1.0000x reference)
//
#include <hip/hip_runtime.h>

// SimpleGRU scan: B=2048 seqs, T=2048 steps, H=32, O=2, fp32 backbone.
// Round-6: R5 structure (1 batch/wave, 2048 waves = 2/SIMD, split-K lane
// pairs, fdot2 gate matmul) with the two measured pathologies removed:
//  (a) AGPR tax: VGPR_Count 68/48/80/32 across R1-R5 + 3.2 cyc/instr marginal
//      cost = allocator parks long-lived values in AGPRs, ~2cyc/use tax.
//      Fix: weights live in LDS (f16x2 table, 6 KiB), re-read per step as
//      6x ds_read_b128 (LDS pipe, latency hidden - they don't depend on h).
//      A per-step opaque asm touch of the address reg defeats hoisting.
//  (b) serial LDS round-trip (~240 cyc) for the h exchange. Fix: in-register
//      f16 pair pack (cvt + quad_perm DPP + cndmask + lshl_or) then 8
//      INDEPENDENT ds_bpermute_b32 gathers (~130 cyc overlapped).

typedef _Float16 f16x2 __attribute__((ext_vector_type(2)));

__device__ __forceinline__ float sigmoid_fast(float s) {
    float e = __builtin_amdgcn_exp2f(s * -1.44269504088896340736f);
    return __builtin_amdgcn_rcpf(1.0f + e);
}

__device__ __forceinline__ float tanh_fast(float u) {
    float e = __builtin_amdgcn_exp2f(u * 2.88539008177792681472f);
    float r = __builtin_amdgcn_rcpf(1.0f + e);
    return fmaf(-2.0f, r, 1.0f);
}

// v + (v from partner lane l^1), via DPP quad_perm [1,0,3,2] (ctrl 0xB1).
__device__ __forceinline__ float xor1_add(float v) {
    int i = __float_as_int(v);
    int s = __builtin_amdgcn_update_dpp(i, i, 0xB1, 0xF, 0xF, true);
    return v + __int_as_float(s);
}

__device__ __forceinline__ float fdot2(int a, int b, float c) {
    return __builtin_amdgcn_fdot2(__builtin_bit_cast(f16x2, a),
                                  __builtin_bit_cast(f16x2, b), c, false);
}

__device__ __forceinline__ unsigned int pack_pair(float a, float b) {
    f16x2 p;
    p.x = (_Float16)a;
    p.y = (_Float16)b;
    return __builtin_bit_cast(unsigned int, p);
}

__global__ __launch_bounds__(64, 2)
void gru_scan_kernel(const float* __restrict__ x,      // [B,T]
                     const float* __restrict__ w_ih,   // [96,1]
                     const float* __restrict__ w_hh,   // [96,32]
                     const float* __restrict__ b_ih,   // [96]
                     const float* __restrict__ b_hh,   // [96]
                     const float* __restrict__ head_w, // [2,32]
                     const float* __restrict__ head_b, // [2]
                     float* __restrict__ out,          // [B,2]
                     int T)
{
    const int l    = (int)threadIdx.x;
    const int j    = l >> 1;    // hidden/gate index, 0..31
    const int half = l & 1;     // K-split half
    const int b    = (int)blockIdx.x;

    // W2[row][pc]: f16x2 pair (w[row][2pc], w[row][2pc+1]), row-major, no pad
    // (b128 16B-aligned; multi-sweep aliasing is structural, not a conflict).
    __shared__ __align__(16) unsigned int W2[96 * 16];
    __shared__ __align__(16) float x_s[2][64];
    __shared__ float hf_s[32];

    // ---- one-time: stage w_hh as f16 pairs into LDS ----
    for (int idx = l; idx < 96 * 16; idx += 64) {
        const int row = idx >> 4, pc = idx & 15;
        W2[idx] = pack_pair(w_hh[row * 32 + 2 * pc], w_hh[row * 32 + 2 * pc + 1]);
    }

    // seeds pre-scaled so only half 0 contributes bias + x-gate terms for
    // r/z and the bnh term for n (xor-combine then counts each once)
    const float hsel   = (half == 0) ? 1.0f : 0.0f;
    const float wihr_e = w_ih[j]      * hsel;
    const float wihz_e = w_ih[32 + j] * hsel;
    const float br_e   = (b_ih[j]      + b_hh[j])      * hsel;
    const float bz_e   = (b_ih[32 + j] + b_hh[32 + j]) * hsel;
    const float bnh_e  = b_hh[64 + j] * hsel;
    const float wihn   = w_ih[64 + j];   // post-combine, both halves
    const float bni    = b_ih[64 + j];

    const float* xrow   = x + (size_t)b * (size_t)T;
    const int    nchunk = T >> 6;   // 64-step chunks (T=2048 -> 32)

    // weight read base (bytes): row j, pair-col 8*half; gates at +2048/+4096
    int waddr = j * 64 + half * 32;
    // bpermute byte index base: pair m=8*half+i lives in lane 4m -> 16*m
    const int bidx = half * 128;
    const bool hi_sel = (l & 2) != 0;   // pair-pack operand order

    float h = 0.0f;
    int P0 = 0, P1 = 0, P2 = 0, P3 = 0, P4 = 0, P5 = 0, P6 = 0, P7 = 0;
    x_s[0][l] = xrow[l];
    float xnext = (nchunk > 1) ? xrow[64 + l] : 0.0f;
    __builtin_amdgcn_wave_barrier();

    for (int c = 0; c < nchunk; ++c) {
        const int buf = c & 1;
        const float* xs = &x_s[buf][0];
        for (int s4 = 0; s4 < 64; s4 += 4) {
            const float4 xq = *(const float4*)(xs + s4);  // uniform b128
#pragma unroll
            for (int s = 0; s < 4; ++s) {
                const float xv = (s == 0) ? xq.x : (s == 1) ? xq.y
                               : (s == 2) ? xq.z : xq.w;
                // per-step weight reads (defeat hoisting via opaque touch);
                // independent of h -> latency overlaps the activation tail
                asm volatile("" : "+v"(waddr));
                const char* wb = ((const char*)W2) + waddr;
                const uint4 WRa = *(const uint4*)(wb);
                const uint4 WRb = *(const uint4*)(wb + 16);
                const uint4 WZa = *(const uint4*)(wb + 2048);
                const uint4 WZb = *(const uint4*)(wb + 2064);
                const uint4 WNa = *(const uint4*)(wb + 4096);
                const uint4 WNb = *(const uint4*)(wb + 4112);

                // 2 chains of 4 fdot2 per gate (8 pairs = 16 MACs)
                float rA = fdot2(P0, WRa.x, fmaf(xv, wihr_e, br_e));
                float zA = fdot2(P0, WZa.x, fmaf(xv, wihz_e, bz_e));
                float nA = fdot2(P0, WNa.x, bnh_e);
                rA = fdot2(P1, WRa.y, rA); zA = fdot2(P1, WZa.y, zA); nA = fdot2(P1, WNa.y, nA);
                rA = fdot2(P2, WRa.z, rA); zA = fdot2(P2, WZa.z, zA); nA = fdot2(P2, WNa.z, nA);
                rA = fdot2(P3, WRa.w, rA); zA = fdot2(P3, WZa.w, zA); nA = fdot2(P3, WNa.w, nA);

                float rB = fdot2(P4, WRb.x, 0.0f);
                float zB = fdot2(P4, WZb.x, 0.0f);
                float nB = fdot2(P4, WNb.x, 0.0f);
                rB = fdot2(P5, WRb.y, rB); zB = fdot2(P5, WZb.y, zB); nB = fdot2(P5, WNb.y, nB);
                rB = fdot2(P6, WRb.z, rB); zB = fdot2(P6, WZb.z, zB); nB = fdot2(P6, WNb.z, nB);
                rB = fdot2(P7, WRb.w, rB); zB = fdot2(P7, WZb.w, zB); nB = fdot2(P7, WNb.w, nB);

                // combine own halves, then partner lane via DPP xor-1 add
                const float rp = xor1_add(rA + rB);
                const float zp = xor1_add(zA + zB);
                const float np = xor1_add(nA + nB);

                const float r  = sigmoid_fast(rp);
                const float z  = sigmoid_fast(zp);
                const float xn = fmaf(xv, wihn, bni);
                const float n  = tanh_fast(fmaf(r, np, xn));
                h = fmaf(z, h - n, n);               // (1-z)*n + z*h

                // ---- h exchange: in-register pack + bpermute gather ----
                // quad m holds h_{2m} (lanes 4m,4m+1) and h_{2m+1} (+2,+3)
                const unsigned short h16u =
                    __builtin_bit_cast(unsigned short, (_Float16)h);
                const int own = (int)h16u;
                const int oth = __builtin_amdgcn_update_dpp(own, own, 0x4E,
                                                            0xF, 0xF, true);
                const int lo = hi_sel ? oth : own;   // h_{2m} (even k)
                const int hi = hi_sel ? own : oth;   // h_{2m+1} (odd k)
                const int pk = lo | (hi << 16);      // f16x2 pair m = l>>2
                P0 = __builtin_amdgcn_ds_bpermute(bidx +   0, pk);
                P1 = __builtin_amdgcn_ds_bpermute(bidx +  16, pk);
                P2 = __builtin_amdgcn_ds_bpermute(bidx +  32, pk);
                P3 = __builtin_amdgcn_ds_bpermute(bidx +  48, pk);
                P4 = __builtin_amdgcn_ds_bpermute(bidx +  64, pk);
                P5 = __builtin_amdgcn_ds_bpermute(bidx +  80, pk);
                P6 = __builtin_amdgcn_ds_bpermute(bidx +  96, pk);
                P7 = __builtin_amdgcn_ds_bpermute(bidx + 112, pk);
            }
        }
        if (c + 1 < nchunk) {
            x_s[1 - buf][l] = xnext;                 // stage next chunk
            if (c + 2 < nchunk) xnext = xrow[(c + 2) * 64 + l];
            __builtin_amdgcn_wave_barrier();
        }
    }

    // ---- head: out[b,o] = head_b[o] + sum_k h[k]*head_w[o,k] (fp32 h) ----
    hf_s[j] = h;                                     // both half-lanes: same val
    __builtin_amdgcn_wave_barrier();
    if (l < 2) {
        float acc = head_b[l];
        const float* hw = head_w + l * 32;
#pragma unroll
        for (int k = 0; k < 32; ++k) acc = fmaf(hf_s[k], hw[k], acc);
        out[b * 2 + l] = acc;
    }
}

extern "C" void kernel_launch(void* const* d_in, const int* in_sizes, int n_in,
                              void* d_out, int out_size, void* d_ws, size_t ws_size,
                              hipStream_t stream) {
    const float* x      = (const float*)d_in[0];
    const float* w_ih   = (const float*)d_in[1];
    const float* w_hh   = (const float*)d_in[2];
    const float* b_ih   = (const float*)d_in[3];
    const float* b_hh   = (const float*)d_in[4];
    const float* head_w = (const float*)d_in[5];
    const float* head_b = (const float*)d_in[6];
    float* out = (float*)d_out;

    const int B = out_size / 2;          // O = 2
    const int T = in_sizes[0] / B;       // x is [B,T]

    dim3 grid(B), block(64);
    hipLaunchKernelGGL(gru_scan_kernel, grid, block, 0, stream,
                       x, w_ih, w_hh, b_ih, b_hh, head_w, head_b, out, T);
}

// Round 7
// 637.661 us; speedup vs baseline: 1.2725x; 1.2725x over previous
//
#include <hip/hip_runtime.h>

// SimpleGRU scan: B=2048 seqs, T=2048 steps, H=32, O=2, fp32.
// Round-7: R5 skeleton (split-K2 lane pairs, 1 batch/wave, 2048 waves =
// 2 waves/SIMD = max TLP without cross-wave reduction), with:
//  * gate matmul via v_pk_fma_f32 (packed fp32, full-rate 2-MAC): re-fit of
//    R3/R4/R5 issue counts suggests v_dot2_f32_f16 is half-rate, so R5's
//    fdot2s bought nothing over FMA. pk_fma_f32 also restores fp32 accuracy.
//  * weights register-resident (R6 proved LDS weights die on bank conflicts
//    AND LDS-pipe bandwidth: 1.68e8 conflicts, 811 us).
//  * h exchange back to f32 LDS write-b32 / 4x b128 broadcast reads (two
//    distinct addresses per read -> conflict-free; R5-style, latency hidden
//    by the co-resident wave).
//  * shared-rcp sigmoids: r,z = 1/(1+e) pair via 2 exp + 1 rcp (P=AB trick).
//  * x staged in registers (float4 load per 4 steps, double-buffered) -- no
//    x LDS, no staging barriers.

typedef float f32x2 __attribute__((ext_vector_type(2)));

// v + (v from partner lane l^1), via DPP quad_perm [1,0,3,2] (ctrl 0xB1).
__device__ __forceinline__ float xor1_add(float v) {
    int i = __float_as_int(v);
    int s = __builtin_amdgcn_update_dpp(i, i, 0xB1, 0xF, 0xF, true);
    return v + __int_as_float(s);
}

__global__ __launch_bounds__(64, 2)
void gru_scan_kernel(const float* __restrict__ x,      // [B,T]
                     const float* __restrict__ w_ih,   // [96,1]
                     const float* __restrict__ w_hh,   // [96,32]
                     const float* __restrict__ b_ih,   // [96]
                     const float* __restrict__ b_hh,   // [96]
                     const float* __restrict__ head_w, // [2,32]
                     const float* __restrict__ head_b, // [2]
                     float* __restrict__ out,          // [B,2]
                     int T)
{
    const int l    = (int)threadIdx.x;
    const int j    = l >> 1;    // hidden/gate index, 0..31
    const int half = l & 1;     // K-split half
    const int b    = (int)blockIdx.x;

    __shared__ __align__(16) float h_s[32];

    // ---- per-lane weights: 16 f32 per gate as 8 f32x2, register-pinned ----
    f32x2 WR[8], WZ[8], WN[8];
    {
        const f32x2* pR = (const f32x2*)(w_hh + (     j) * 32 + half * 16);
        const f32x2* pZ = (const f32x2*)(w_hh + (32 + j) * 32 + half * 16);
        const f32x2* pN = (const f32x2*)(w_hh + (64 + j) * 32 + half * 16);
#pragma unroll
        for (int q = 0; q < 8; ++q) { WR[q] = pR[q]; WZ[q] = pZ[q]; WN[q] = pN[q]; }
    }
#pragma unroll
    for (int q = 0; q < 8; ++q) {
        asm volatile("" : "+v"(WR[q]));
        asm volatile("" : "+v"(WZ[q]));
        asm volatile("" : "+v"(WN[q]));
    }

    // seeds pre-scaled so only half 0 contributes bias + x-gate terms for
    // r/z and the bnh term for n (xor-combine then counts each once)
    const float hsel   = (half == 0) ? 1.0f : 0.0f;
    const float wihr_e = w_ih[j]      * hsel;
    const float wihz_e = w_ih[32 + j] * hsel;
    const float br_e   = (b_ih[j]      + b_hh[j])      * hsel;
    const float bz_e   = (b_ih[32 + j] + b_hh[32 + j]) * hsel;
    const float bnh_e  = b_hh[64 + j] * hsel;
    const float wihn   = w_ih[64 + j];   // post-combine, both halves
    const float bni    = b_ih[64 + j];

    const float*  xrow  = x + (size_t)b * (size_t)T;
    const float4* xrow4 = (const float4*)xrow;     // 8KB-aligned (T=2048)
    const int     n4    = T >> 2;                  // 512 groups of 4 steps
    const int     t4max = n4 - 1;

    float h = 0.0f;
    h_s[j] = 0.0f;                       // lanes 2j,2j+1: same value, ok
    __builtin_amdgcn_wave_barrier();

    // h read base: 16 floats of own half = 4x float4 broadcast reads
    const float4* hq = (const float4*)(h_s + half * 16);

    float4 xcur = xrow4[0];
    float4 xnxt = xrow4[1 <= t4max ? 1 : 0];

    for (int t4 = 0; t4 < n4; ++t4) {
        const float4 xg = xcur;
        xcur = xnxt;
        const int nidx = (t4 + 2 <= t4max) ? (t4 + 2) : t4max;
        xnxt = xrow4[nidx];              // consumed 4 steps later: hidden
#pragma unroll
        for (int s = 0; s < 4; ++s) {
            const float xv = (s == 0) ? xg.x : (s == 1) ? xg.y
                           : (s == 2) ? xg.z : xg.w;
            // 16 h values of own half as 4 broadcast b128 reads
            const float4 ha = hq[0], hb = hq[1], hc = hq[2], hd = hq[3];
            const f32x2 H0 = { ha.x, ha.y }, H1 = { ha.z, ha.w };
            const f32x2 H2 = { hb.x, hb.y }, H3 = { hb.z, hb.w };
            const f32x2 H4 = { hc.x, hc.y }, H5 = { hc.z, hc.w };
            const f32x2 H6 = { hd.x, hd.y }, H7 = { hd.z, hd.w };

            // 2 chains of 4 packed FMAs per gate (16 MACs)
            f32x2 cR0 = H0 * WR[0], cZ0 = H0 * WZ[0], cN0 = H0 * WN[0];
            f32x2 cR1 = H1 * WR[1], cZ1 = H1 * WZ[1], cN1 = H1 * WN[1];
            cR0 = __builtin_elementwise_fma(H2, WR[2], cR0);
            cZ0 = __builtin_elementwise_fma(H2, WZ[2], cZ0);
            cN0 = __builtin_elementwise_fma(H2, WN[2], cN0);
            cR1 = __builtin_elementwise_fma(H3, WR[3], cR1);
            cZ1 = __builtin_elementwise_fma(H3, WZ[3], cZ1);
            cN1 = __builtin_elementwise_fma(H3, WN[3], cN1);
            cR0 = __builtin_elementwise_fma(H4, WR[4], cR0);
            cZ0 = __builtin_elementwise_fma(H4, WZ[4], cZ0);
            cN0 = __builtin_elementwise_fma(H4, WN[4], cN0);
            cR1 = __builtin_elementwise_fma(H5, WR[5], cR1);
            cZ1 = __builtin_elementwise_fma(H5, WZ[5], cZ1);
            cN1 = __builtin_elementwise_fma(H5, WN[5], cN1);
            cR0 = __builtin_elementwise_fma(H6, WR[6], cR0);
            cZ0 = __builtin_elementwise_fma(H6, WZ[6], cZ0);
            cN0 = __builtin_elementwise_fma(H6, WN[6], cN0);
            cR1 = __builtin_elementwise_fma(H7, WR[7], cR1);
            cZ1 = __builtin_elementwise_fma(H7, WZ[7], cZ1);
            cN1 = __builtin_elementwise_fma(H7, WN[7], cN1);

            const f32x2 sR = cR0 + cR1;   // v_pk_add_f32
            const f32x2 sZ = cZ0 + cZ1;
            const f32x2 sN = cN0 + cN1;

            // horizontal + seed (seed half-scaled -> counted once), then
            // partner-lane combine via DPP xor-1 add
            const float seedR = fmaf(xv, wihr_e, br_e);
            const float seedZ = fmaf(xv, wihz_e, bz_e);
            const float rp = xor1_add((sR.x + seedR) + sR.y);
            const float zp = xor1_add((sZ.x + seedZ) + sZ.y);
            const float np = xor1_add((sN.x + bnh_e) + sN.y);

            // shared-rcp sigmoid pair: r=1/(1+er), z=1/(1+ez)
            const float er = __builtin_amdgcn_exp2f(rp * -1.44269504088896f);
            const float ez = __builtin_amdgcn_exp2f(zp * -1.44269504088896f);
            const float A  = 1.0f + er;
            const float Bv = 1.0f + ez;
            const float inv = __builtin_amdgcn_rcpf(A * Bv);
            const float r  = Bv * inv;
            const float z  = A * inv;

            // n = tanh(xn + r*np)
            const float xn = fmaf(xv, wihn, bni);
            const float u  = fmaf(r, np, xn);
            const float et = __builtin_amdgcn_exp2f(u * 2.88539008177793f);
            const float ti = __builtin_amdgcn_rcpf(1.0f + et);
            const float n  = fmaf(-2.0f, ti, 1.0f);

            h = fmaf(z, h - n, n);               // (1-z)*n + z*h
            __builtin_amdgcn_wave_barrier();
            h_s[j] = h;                          // pair-lanes: same value
            __builtin_amdgcn_wave_barrier();     // in-order DS => RAW safe
        }
    }

    // ---- head: out[b,o] = head_b[o] + sum_k h[k]*head_w[o,k] ----
    __builtin_amdgcn_wave_barrier();
    if (l < 2) {
        float acc = head_b[l];
        const float* hw = head_w + l * 32;
#pragma unroll
        for (int k = 0; k < 32; ++k) acc = fmaf(h_s[k], hw[k], acc);
        out[b * 2 + l] = acc;
    }
}

extern "C" void kernel_launch(void* const* d_in, const int* in_sizes, int n_in,
                              void* d_out, int out_size, void* d_ws, size_t ws_size,
                              hipStream_t stream) {
    const float* x      = (const float*)d_in[0];
    const float* w_ih   = (const float*)d_in[1];
    const float* w_hh   = (const float*)d_in[2];
    const float* b_ih   = (const float*)d_in[3];
    const float* b_hh   = (const float*)d_in[4];
    const float* head_w = (const float*)d_in[5];
    const float* head_b = (const float*)d_in[6];
    float* out = (float*)d_out;

    const int B = out_size / 2;          // O = 2
    const int T = in_sizes[0] / B;       // x is [B,T]

    dim3 grid(B), block(64);
    hipLaunchKernelGGL(gru_scan_kernel, grid, block, 0, stream,
                       x, w_ih, w_hh, b_ih, b_hh, head_w, head_b, out, T);
}

// Round 8
// 465.263 us; speedup vs baseline: 1.7440x; 1.3705x over previous
//
#include <hip/hip_runtime.h>

// SimpleGRU scan: B=2048 seqs, T=2048 steps, H=32, O=2, fp32 backbone.
// Round-8: full-K 2-batch/wave mapping (lane j = batch-A gate j, lane 32+j =
// batch-B gate j), f16 dot2 gate matmul. Model fitted across R1-R7:
// trans~8cyc, dot2/pk~4cyc, fma 2cyc, AGPR-parking tax above ~24-32 live regs.
// Full-K shares ONE set of trans/update instructions across 2 batches and
// needs no DPP combines (split-K paid trans 48 + dpp 24 + combine 24 PER
// batch). f16 pair weights halve full-K's register bill vs fp32 (48 regs,
// not 96 -> R3's 150cyc tax territory avoided). 1024 waves -> 1 wave/SIMD:
// h LDS round-trip exposed (~110cyc/step) -- accepted; issue/batch drops
// 259 -> ~141-175.
//  * h exchange: f16 LDS, group-disjoint banks (group0 bytes 0-63 = banks
//    0-15, group1 bytes 64-127 = banks 16-31; write_b16 2-way = free).
//  * x staged in LDS per group (R1 pattern), 32-step chunks, double-buffered.
//  * shared-rcp sigmoid pair (3 exp + 2 rcp total per step for 2 batches).

typedef _Float16 f16x2 __attribute__((ext_vector_type(2)));

__device__ __forceinline__ float fdot2(int a, int b, float c) {
    return __builtin_amdgcn_fdot2(__builtin_bit_cast(f16x2, a),
                                  __builtin_bit_cast(f16x2, b), c, false);
}

__device__ __forceinline__ int pack_pair(float a, float b) {
    f16x2 p;
    p.x = (_Float16)a;
    p.y = (_Float16)b;
    return __builtin_bit_cast(int, p);
}

__global__ __launch_bounds__(64, 1)
void gru_scan_kernel(const float* __restrict__ x,      // [B,T]
                     const float* __restrict__ w_ih,   // [96,1]
                     const float* __restrict__ w_hh,   // [96,32]
                     const float* __restrict__ b_ih,   // [96]
                     const float* __restrict__ b_hh,   // [96]
                     const float* __restrict__ head_w, // [2,32]
                     const float* __restrict__ head_b, // [2]
                     float* __restrict__ out,          // [B,2]
                     int T)
{
    const int l = (int)threadIdx.x;
    const int g = l >> 5;   // batch slot within wave
    const int j = l & 31;   // gate/hidden row
    const int b = (int)blockIdx.x * 2 + g;

    __shared__ __align__(16) _Float16 h16[2][32];   // [group][hidden] f16
    __shared__ float hf_s[2][32];                   // fp32 h for head
    __shared__ __align__(16) float x_s[2][2][32];   // [group][buf][step]

    // ---- per-lane weights: rows j (r), 32+j (z), 64+j (n), full K=32,
    // as 16 f16x2 pairs per gate = 48 int regs, asm-pinned ----
    int wR[16], wZ[16], wN[16];
    {
        const float* pR = w_hh + (     j) * 32;
        const float* pZ = w_hh + (32 + j) * 32;
        const float* pN = w_hh + (64 + j) * 32;
#pragma unroll
        for (int q = 0; q < 16; ++q) {
            wR[q] = pack_pair(pR[2*q], pR[2*q+1]);
            wZ[q] = pack_pair(pZ[2*q], pZ[2*q+1]);
            wN[q] = pack_pair(pN[2*q], pN[2*q+1]);
        }
    }
#pragma unroll
    for (int q = 0; q < 16; ++q) {
        asm volatile("" : "+v"(wR[q]), "+v"(wZ[q]), "+v"(wN[q]));
    }

    // full-K: every lane computes complete dots -> plain per-row seeds
    const float wihr = w_ih[j];
    const float wihz = w_ih[32 + j];
    const float wihn = w_ih[64 + j];
    const float br   = b_ih[j]      + b_hh[j];
    const float bz   = b_ih[32 + j] + b_hh[32 + j];
    const float bni  = b_ih[64 + j];
    const float bnh  = b_hh[64 + j];

    const float* xrow   = x + (size_t)b * (size_t)T;
    const int    nchunk = T >> 5;   // 32-step chunks (T=2048 -> 64)

    float h = 0.0f;
    h16[g][j]    = (_Float16)0.0f;
    x_s[g][0][j] = xrow[j];
    float xnext  = (nchunk > 1) ? xrow[32 + j] : 0.0f;
    __builtin_amdgcn_wave_barrier();

    // own group's 32 h = 64 B = 4 broadcast b128 reads (group-disjoint banks)
    const int4* hq = (const int4*)(&h16[g][0]);

    for (int c = 0; c < nchunk; ++c) {
        const int buf = c & 1;
        const float* xs = &x_s[g][buf][0];
#pragma unroll 4
        for (int s = 0; s < 32; ++s) {
            const float xv = xs[s];                  // broadcast b32
            const int4 H0 = hq[0];   // h pairs 0..3
            const int4 H1 = hq[1];   // pairs 4..7
            const int4 H2 = hq[2];   // pairs 8..11
            const int4 H3 = hq[3];   // pairs 12..15

            // 2 chains of 8 dot2 per gate (16 pairs = full K=32)
            float rA = fdot2(H0.x, wR[ 0], fmaf(xv, wihr, br));
            float zA = fdot2(H0.x, wZ[ 0], fmaf(xv, wihz, bz));
            float nA = fdot2(H0.x, wN[ 0], bnh);
            rA = fdot2(H0.y, wR[ 1], rA); zA = fdot2(H0.y, wZ[ 1], zA); nA = fdot2(H0.y, wN[ 1], nA);
            rA = fdot2(H0.z, wR[ 2], rA); zA = fdot2(H0.z, wZ[ 2], zA); nA = fdot2(H0.z, wN[ 2], nA);
            rA = fdot2(H0.w, wR[ 3], rA); zA = fdot2(H0.w, wZ[ 3], zA); nA = fdot2(H0.w, wN[ 3], nA);
            rA = fdot2(H1.x, wR[ 4], rA); zA = fdot2(H1.x, wZ[ 4], zA); nA = fdot2(H1.x, wN[ 4], nA);
            rA = fdot2(H1.y, wR[ 5], rA); zA = fdot2(H1.y, wZ[ 5], zA); nA = fdot2(H1.y, wN[ 5], nA);
            rA = fdot2(H1.z, wR[ 6], rA); zA = fdot2(H1.z, wZ[ 6], zA); nA = fdot2(H1.z, wN[ 6], nA);
            rA = fdot2(H1.w, wR[ 7], rA); zA = fdot2(H1.w, wZ[ 7], zA); nA = fdot2(H1.w, wN[ 7], nA);

            float rB = fdot2(H2.x, wR[ 8], 0.0f);
            float zB = fdot2(H2.x, wZ[ 8], 0.0f);
            float nB = fdot2(H2.x, wN[ 8], 0.0f);
            rB = fdot2(H2.y, wR[ 9], rB); zB = fdot2(H2.y, wZ[ 9], zB); nB = fdot2(H2.y, wN[ 9], nB);
            rB = fdot2(H2.z, wR[10], rB); zB = fdot2(H2.z, wZ[10], zB); nB = fdot2(H2.z, wN[10], nB);
            rB = fdot2(H2.w, wR[11], rB); zB = fdot2(H2.w, wZ[11], zB); nB = fdot2(H2.w, wN[11], nB);
            rB = fdot2(H3.x, wR[12], rB); zB = fdot2(H3.x, wZ[12], zB); nB = fdot2(H3.x, wN[12], nB);
            rB = fdot2(H3.y, wR[13], rB); zB = fdot2(H3.y, wZ[13], zB); nB = fdot2(H3.y, wN[13], nB);
            rB = fdot2(H3.z, wR[14], rB); zB = fdot2(H3.z, wZ[14], zB); nB = fdot2(H3.z, wN[14], nB);
            rB = fdot2(H3.w, wR[15], rB); zB = fdot2(H3.w, wZ[15], zB); nB = fdot2(H3.w, wN[15], nB);

            const float rp = rA + rB;
            const float zp = zA + zB;
            const float np = nA + nB;

            // shared-rcp sigmoid pair: r=1/(1+er), z=1/(1+ez)
            const float er = __builtin_amdgcn_exp2f(rp * -1.44269504088896f);
            const float ez = __builtin_amdgcn_exp2f(zp * -1.44269504088896f);
            const float A  = 1.0f + er;
            const float Bv = 1.0f + ez;
            const float inv = __builtin_amdgcn_rcpf(A * Bv);
            const float r  = Bv * inv;
            const float z  = A * inv;

            // n = tanh(xn + r*np)
            const float xn = fmaf(xv, wihn, bni);
            const float u  = fmaf(r, np, xn);
            const float et = __builtin_amdgcn_exp2f(u * 2.88539008177793f);
            const float ti = __builtin_amdgcn_rcpf(1.0f + et);
            const float n  = fmaf(-2.0f, ti, 1.0f);

            h = fmaf(z, h - n, n);                   // (1-z)*n + z*h
            __builtin_amdgcn_wave_barrier();
            h16[g][j] = (_Float16)h;                 // publish for next step
            __builtin_amdgcn_wave_barrier();         // in-order DS => RAW safe
        }
        if (c + 1 < nchunk) {
            x_s[g][1 - buf][j] = xnext;              // stage next chunk
            if (c + 2 < nchunk) xnext = xrow[(c + 2) * 32 + j];
            __builtin_amdgcn_wave_barrier();
        }
    }

    // ---- head: out[b,o] = head_b[o] + sum_k h[k]*head_w[o,k] (fp32 h) ----
    hf_s[g][j] = h;
    __builtin_amdgcn_wave_barrier();
    if (l < 4) {
        const int g2 = l >> 1, o = l & 1;
        float acc = head_b[o];
        const float* hw = head_w + o * 32;
#pragma unroll
        for (int k = 0; k < 32; ++k) acc = fmaf(hf_s[g2][k], hw[k], acc);
        out[((int)blockIdx.x * 2 + g2) * 2 + o] = acc;
    }
}

extern "C" void kernel_launch(void* const* d_in, const int* in_sizes, int n_in,
                              void* d_out, int out_size, void* d_ws, size_t ws_size,
                              hipStream_t stream) {
    const float* x      = (const float*)d_in[0];
    const float* w_ih   = (const float*)d_in[1];
    const float* w_hh   = (const float*)d_in[2];
    const float* b_ih   = (const float*)d_in[3];
    const float* b_hh   = (const float*)d_in[4];
    const float* head_w = (const float*)d_in[5];
    const float* head_b = (const float*)d_in[6];
    float* out = (float*)d_out;

    const int B = out_size / 2;          // O = 2
    const int T = in_sizes[0] / B;       // x is [B,T]

    dim3 grid(B / 2), block(64);
    hipLaunchKernelGGL(gru_scan_kernel, grid, block, 0, stream,
                       x, w_ih, w_hh, b_ih, b_hh, head_w, head_b, out, T);
}